// Round 7
// baseline (63.015 us; speedup 1.0000x reference)
//
#include <hip/hip_runtime.h>

// Problem constants (fixed by setup_inputs)
#define K   19
#define C   256
#define HF  64
#define WF  128
#define HW  (HF * WF)
#define BB  4
#define HL  512
#define WL  1024

// f32 near-tie threshold: f32 distance error bound < ~1e-3; pixels whose
// top-2 f32 gap < TAU get an exact f64 recompute (rare; exact==np, R1-R6).
#define TAU 0.015f

#define CTW 20                    // padded row width of transposed table
// ---- workspace layout ----
// f32[0      .. 5120)  : ct map0, [C][20] transposed centroids (pad col 19 = 0)
// f32[5120   .. 10240) : ct map1
// f32[10240  .. 10259) : c2f map0;  f32[10259 .. 10278): c2f map1
// byte 41120           : c2d map0 [19 f64], c2d map1 [19 f64]
#define WS_CT1      5120
#define WS_C2F      10240
#define WS_C2D_BYTE 41120
#define WS_NEED     (WS_C2D_BYTE + 2 * K * 8)

// ---------- setup: transpose centroids to [C][20] + exact ||c||^2 ----------
__global__ __launch_bounds__(256) void centroid_setup_kernel(
    const float* __restrict__ cent0,   // map 0 centroids (centroid_target)
    const float* __restrict__ cent1,   // map 1 centroids (centroid_s2t)
    float* __restrict__ ws)
{
    __shared__ double c2p[K][8];
    const int map = blockIdx.x;
    const float* __restrict__ cent = (map == 0) ? cent0 : cent1;
    float* __restrict__ ct  = ws + map * WS_CT1;
    float* __restrict__ c2f = ws + WS_C2F + map * K;
    double* __restrict__ c2d = (double*)((char*)ws + WS_C2D_BYTE) + map * K;

    const int tid = threadIdx.x;
    for (int idx = tid; idx < K * C; idx += 256) {
        int k = idx >> 8, c = idx & (C - 1);
        ct[c * CTW + k] = cent[idx];
    }
    for (int c = tid; c < C; c += 256) ct[c * CTW + K] = 0.f;   // pad col
    if (tid < K * 8) {
        const int k = tid >> 3, sl = tid & 7;
        const float* cp = cent + k * C + sl * 32;
        double s = 0.0;
        #pragma unroll
        for (int j = 0; j < 32; ++j) { double v = (double)cp[j]; s = fma(v, v, s); }
        c2p[k][sl] = s;
    }
    __syncthreads();
    if (tid < K) {
        double s = 0.0;
        #pragma unroll
        for (int j = 0; j < 8; ++j) s += c2p[tid][j];
        c2d[tid] = s;
        c2f[tid] = (float)s;
    }
}

// ---------- main: 1 px/thread, c-outer / k-inner, centroids in LDS ----------
// Per channel: ONE streaming per-lane feature load (consumed immediately) +
// 5 wave-uniform float4 LDS reads (broadcast, conflict-free) + 19 FMAs into
// acc[19]. No s_load chain, no feature re-loads, one barrier, no cross-wave
// reduction.
__global__ __launch_bounds__(256, 1) void centroid_mask_kernel(
    const float* __restrict__ feat0,
    const float* __restrict__ feat1,
    const float* __restrict__ ws,
    int* __restrict__ out)
{
    __shared__ __align__(16) float ctl[C * CTW];   // 20480 B
    __shared__ float c2fl[K];

    const int map = blockIdx.y;
    const float* __restrict__ feat = (map == 0) ? feat0 : feat1;
    const float* __restrict__ ctm  = ws + map * WS_CT1;

    const int tid = threadIdx.x;

    // stage centroid table + c2f into LDS (coalesced)
    for (int i = tid; i < C * CTW; i += 256) ctl[i] = ctm[i];
    if (tid < K) c2fl[tid] = ws[WS_C2F + map * K + tid];
    __syncthreads();

    const int p  = blockIdx.x * 256 + tid;   // 0 .. 32767
    const int hw = p & (HW - 1);
    const int b  = p >> 13;

    const float* __restrict__ fp = feat + (size_t)b * C * HW + hw;

    float acc[K];
    #pragma unroll
    for (int k = 0; k < K; ++k) acc[k] = 0.f;

    #pragma unroll 2
    for (int c = 0; c < C; c += 2) {
        float fa = fp[(size_t)c * HW];
        float fb = fp[(size_t)(c + 1) * HW];
        const float4* __restrict__ ra = (const float4*)&ctl[c * CTW];
        const float4* __restrict__ rb = (const float4*)&ctl[(c + 1) * CTW];
        float4 a0 = ra[0], a1 = ra[1], a2 = ra[2], a3 = ra[3], a4 = ra[4];
        float4 b0 = rb[0], b1 = rb[1], b2 = rb[2], b3 = rb[3], b4 = rb[4];
        acc[ 0] = fmaf(fa, a0.x, acc[ 0]); acc[ 1] = fmaf(fa, a0.y, acc[ 1]);
        acc[ 2] = fmaf(fa, a0.z, acc[ 2]); acc[ 3] = fmaf(fa, a0.w, acc[ 3]);
        acc[ 4] = fmaf(fa, a1.x, acc[ 4]); acc[ 5] = fmaf(fa, a1.y, acc[ 5]);
        acc[ 6] = fmaf(fa, a1.z, acc[ 6]); acc[ 7] = fmaf(fa, a1.w, acc[ 7]);
        acc[ 8] = fmaf(fa, a2.x, acc[ 8]); acc[ 9] = fmaf(fa, a2.y, acc[ 9]);
        acc[10] = fmaf(fa, a2.z, acc[10]); acc[11] = fmaf(fa, a2.w, acc[11]);
        acc[12] = fmaf(fa, a3.x, acc[12]); acc[13] = fmaf(fa, a3.y, acc[13]);
        acc[14] = fmaf(fa, a3.z, acc[14]); acc[15] = fmaf(fa, a3.w, acc[15]);
        acc[16] = fmaf(fa, a4.x, acc[16]); acc[17] = fmaf(fa, a4.y, acc[17]);
        acc[18] = fmaf(fa, a4.z, acc[18]);
        acc[ 0] = fmaf(fb, b0.x, acc[ 0]); acc[ 1] = fmaf(fb, b0.y, acc[ 1]);
        acc[ 2] = fmaf(fb, b0.z, acc[ 2]); acc[ 3] = fmaf(fb, b0.w, acc[ 3]);
        acc[ 4] = fmaf(fb, b1.x, acc[ 4]); acc[ 5] = fmaf(fb, b1.y, acc[ 5]);
        acc[ 6] = fmaf(fb, b1.z, acc[ 6]); acc[ 7] = fmaf(fb, b1.w, acc[ 7]);
        acc[ 8] = fmaf(fb, b2.x, acc[ 8]); acc[ 9] = fmaf(fb, b2.y, acc[ 9]);
        acc[10] = fmaf(fb, b2.z, acc[10]); acc[11] = fmaf(fb, b2.w, acc[11]);
        acc[12] = fmaf(fb, b3.x, acc[12]); acc[13] = fmaf(fb, b3.y, acc[13]);
        acc[14] = fmaf(fb, b3.z, acc[14]); acc[15] = fmaf(fb, b3.w, acc[15]);
        acc[16] = fmaf(fb, b4.x, acc[16]); acc[17] = fmaf(fb, b4.y, acc[17]);
        acc[18] = fmaf(fb, b4.z, acc[18]);
    }

    // distances + argmin (strict <, first minimum = np tie-break)
    float d[K];
    #pragma unroll
    for (int k = 0; k < K; ++k) d[k] = c2fl[k] - 2.0f * acc[k];
    int best = 0; float m1 = d[0];
    #pragma unroll
    for (int k = 1; k < K; ++k) if (d[k] < m1) { m1 = d[k]; best = k; }

    unsigned cmask = 0u;
    #pragma unroll
    for (int k = 0; k < K; ++k) if (d[k] - m1 < TAU) cmask |= (1u << k);

    if (cmask & (cmask - 1)) {   // rare near-tie: exact f64 over candidates
        const double* __restrict__ c2d =
            (const double*)((const char*)ws + WS_C2D_BYTE) + map * K;
        double bd = 1e300; int bi = 0;
        for (int k = 0; k < K; ++k) {
            if ((cmask >> k) & 1) {
                double s = 0.0;
                for (int c = 0; c < C; ++c)
                    s = fma((double)fp[(size_t)c * HW], (double)ctl[c * CTW + k], s);
                double dk = c2d[k] - 2.0 * s;
                if (dk < bd) { bd = dk; bi = k; }   // strict <, ascending k
            }
        }
        best = bi;
    }

    // write the 8x8 nearest-upsampled block
    const int w = hw & (WF - 1);
    const int h = hw >> 7;
    int4 v = make_int4(best, best, best, best);
    int* __restrict__ ob = out + (size_t)map * (BB * HL * WL)
                               + (size_t)b * (HL * WL)
                               + (size_t)(h * 8) * WL + (size_t)(w * 8);
    #pragma unroll
    for (int r = 0; r < 8; ++r) {
        *(int4*)(ob + (size_t)r * WL)     = v;
        *(int4*)(ob + (size_t)r * WL + 4) = v;
    }
}

// ---------- safety net (R6 kernel, no workspace) ----------
__global__ __launch_bounds__(512, 4) void centroid_mask_kernel_nows(
    const float* __restrict__ feat0, const float* __restrict__ feat1,
    const float* __restrict__ cent0, const float* __restrict__ cent1,
    int* __restrict__ out)
{
    __shared__ float  part[8 * K * 64];
    __shared__ double c2p[K][8];
    __shared__ double sc2d[K];
    __shared__ float  sc2f[K];
    const int map = blockIdx.y;
    const float* __restrict__ feat = (map == 0) ? feat0 : feat1;
    const float* __restrict__ cent = (map == 0) ? cent0 : cent1;
    const int tid = threadIdx.x, lane = tid & 63;
    const int wv = __builtin_amdgcn_readfirstlane(tid >> 6);
    if (tid < K * 8) {
        const int k = tid >> 3, sl = tid & 7;
        const float* cp = cent + k * C + sl * 32;
        double s = 0.0;
        #pragma unroll
        for (int j = 0; j < 32; ++j) { double v = (double)cp[j]; s = fma(v, v, s); }
        c2p[k][sl] = s;
    }
    const int p = blockIdx.x * 64 + lane;
    const int hw = p & (HW - 1), b = p >> 13, cbase = wv * 32;
    const float* __restrict__ fp = feat + (size_t)b * C * HW + (size_t)cbase * HW + hw;
    float f[32];
    #pragma unroll
    for (int i = 0; i < 32; ++i) f[i] = fp[(size_t)i * HW];
    float* __restrict__ pw = &part[(wv * K) * 64 + lane];
    #pragma unroll
    for (int k = 0; k < K; ++k) {
        const float* __restrict__ ck = cent + (size_t)k * C + cbase;
        float a0 = 0.f, a1 = 0.f, a2 = 0.f, a3 = 0.f;
        #pragma unroll
        for (int j = 0; j < 8; ++j) {
            a0 = fmaf(f[4*j+0], ck[4*j+0], a0);
            a1 = fmaf(f[4*j+1], ck[4*j+1], a1);
            a2 = fmaf(f[4*j+2], ck[4*j+2], a2);
            a3 = fmaf(f[4*j+3], ck[4*j+3], a3);
        }
        pw[k * 64] = (a0 + a1) + (a2 + a3);
    }
    __syncthreads();
    if (tid < K) {
        double s = 0.0;
        #pragma unroll
        for (int j = 0; j < 8; ++j) s += c2p[tid][j];
        sc2d[tid] = s; sc2f[tid] = (float)s;
    }
    __syncthreads();
    if (tid < 64) {
        const int pix = tid;
        float d[K];
        #pragma unroll
        for (int k = 0; k < K; ++k) {
            float s = 0.f;
            #pragma unroll
            for (int w8 = 0; w8 < 8; ++w8) s += part[(w8 * K + k) * 64 + pix];
            d[k] = sc2f[k] - 2.0f * s;
        }
        int best = 0; float m1 = d[0];
        #pragma unroll
        for (int k = 1; k < K; ++k) if (d[k] < m1) { m1 = d[k]; best = k; }
        unsigned cmask = 0u;
        #pragma unroll
        for (int k = 0; k < K; ++k) if (d[k] - m1 < TAU) cmask |= (1u << k);
        if (cmask & (cmask - 1)) {
            const float* __restrict__ fcol = feat + (size_t)b * C * HW + hw;
            double bd = 1e300; int bi = 0;
            for (int k = 0; k < K; ++k) if ((cmask >> k) & 1) {
                const float* __restrict__ ck = cent + (size_t)k * C;
                double s = 0.0;
                for (int c = 0; c < C; ++c)
                    s = fma((double)fcol[(size_t)c * HW], (double)ck[c], s);
                double dk = sc2d[k] - 2.0 * s;
                if (dk < bd) { bd = dk; bi = k; }
            }
            best = bi;
        }
        const int w = hw & (WF - 1), h = hw >> 7;
        int4 v = make_int4(best, best, best, best);
        int* __restrict__ ob = out + (size_t)map * (BB * HL * WL) + (size_t)b * (HL * WL)
                                   + (size_t)(h * 8) * WL + (size_t)(w * 8);
        #pragma unroll
        for (int r = 0; r < 8; ++r) {
            *(int4*)(ob + (size_t)r * WL)     = v;
            *(int4*)(ob + (size_t)r * WL + 4) = v;
        }
    }
}

extern "C" void kernel_launch(void* const* d_in, const int* in_sizes, int n_in,
                              void* d_out, int out_size, void* d_ws, size_t ws_size,
                              hipStream_t stream) {
    const float* feature_s2t     = (const float*)d_in[0];
    const float* feature_target  = (const float*)d_in[1];
    // d_in[2], d_in[3]: labels — only shapes matter, unused
    const float* centroid_s2t    = (const float*)d_in[4];
    const float* centroid_target = (const float*)d_in[5];
    int* out = (int*)d_out;

    if (ws_size >= (size_t)WS_NEED) {
        float* ws = (float*)d_ws;
        hipLaunchKernelGGL(centroid_setup_kernel, dim3(2), dim3(256), 0, stream,
                           centroid_target, centroid_s2t, ws);
        hipLaunchKernelGGL(centroid_mask_kernel, dim3(128, 2), dim3(256), 0, stream,
                           feature_s2t, feature_target, ws, out);
    } else {
        hipLaunchKernelGGL(centroid_mask_kernel_nows, dim3(512, 2), dim3(512), 0, stream,
                           feature_s2t, feature_target,
                           centroid_target, centroid_s2t, out);
    }
}

// Round 8
// 26.498 us; speedup vs baseline: 2.3781x; 2.3781x over previous
//
#include <hip/hip_runtime.h>

// Problem constants (fixed by setup_inputs)
#define K   19
#define C   256
#define HF  64
#define WF  128
#define HW  (HF * WF)
#define BB  4
#define HL  512
#define WL  1024

// f32 near-tie threshold: f32 distance error bound < ~1e-3; pixels whose
// top-2 f32 gap < TAU get an exact f64 recompute (cooperative, see epilogue).
#define TAU 0.015f

// Block = 512 threads = 8 waves, 64 pixels (lane = pixel), wave wv covers
// channels [wv*32, wv*32+32). Main loop identical to R6 (best measured).
// KEY CHANGE vs R6: the exact-f64 near-tie fallback is no longer a 256-deep
// SERIAL per-lane chain (~27us straggler that dominated R4-R7 wall time);
// wave 0 resolves each flagged pixel COOPERATIVELY: 64 lanes x 4 channels,
// f64 butterfly reduce (~1.5K cyc per flagged pixel).
__global__ __launch_bounds__(512, 4) void centroid_mask_kernel(
    const float* __restrict__ feat0,   // feature_s2t
    const float* __restrict__ feat1,   // feature_target
    const float* __restrict__ cent0,   // centroids for map 0 (centroid_target)
    const float* __restrict__ cent1,   // centroids for map 1 (centroid_s2t)
    int* __restrict__ out)             // [2][BB][HL][WL] int32
{
    __shared__ float  part[8 * K * 64];  // [wv][k][pix], pix stride 1: conflict-free
    __shared__ double c2p[K][8];         // exact ||c||^2 partials
    __shared__ double sc2d[K];           // exact ||c||^2 (f64)
    __shared__ float  sc2f[K];           // rounded-exact ||c||^2 (f32)

    const int map = blockIdx.y;
    const float* __restrict__ feat = (map == 0) ? feat0 : feat1;
    const float* __restrict__ cent = (map == 0) ? cent0 : cent1;

    const int tid  = threadIdx.x;
    const int lane = tid & 63;
    const int wv   = __builtin_amdgcn_readfirstlane(tid >> 6);   // 0..7, uniform

    // ---- exact ||c_k||^2 partials (f64), 152 threads, overlaps with preload ----
    if (tid < K * 8) {
        const int k = tid >> 3, sl = tid & 7;
        const float* cp = cent + k * C + sl * 32;
        double s = 0.0;
        #pragma unroll
        for (int j = 0; j < 32; ++j) { double v = (double)cp[j]; s = fma(v, v, s); }
        c2p[k][sl] = s;
    }

    // ---- preload this wave's 32 feature channels for pixel = lane ----
    const int p  = blockIdx.x * 64 + lane;     // pixel in [0, 32768)
    const int hw = p & (HW - 1);
    const int b  = p >> 13;
    const int cbase = wv * 32;

    const float* __restrict__ fp = feat + (size_t)b * C * HW + (size_t)cbase * HW + hw;
    float f[32];
    #pragma unroll
    for (int i = 0; i < 32; ++i) f[i] = fp[(size_t)i * HW];
    __builtin_amdgcn_sched_barrier(0);

    // k-outer: per k, cent[k][cbase..cbase+32) = 32 consecutive dwords at a
    // wave-uniform address (scalar-load eligible).
    float* __restrict__ pw = &part[(wv * K) * 64 + lane];
    #pragma unroll
    for (int k = 0; k < K; ++k) {
        const float* __restrict__ ck = cent + (size_t)k * C + cbase;
        float a0 = 0.f, a1 = 0.f, a2 = 0.f, a3 = 0.f;
        #pragma unroll
        for (int j = 0; j < 8; ++j) {
            a0 = fmaf(f[4*j+0], ck[4*j+0], a0);
            a1 = fmaf(f[4*j+1], ck[4*j+1], a1);
            a2 = fmaf(f[4*j+2], ck[4*j+2], a2);
            a3 = fmaf(f[4*j+3], ck[4*j+3], a3);
        }
        pw[k * 64] = (a0 + a1) + (a2 + a3);   // ds_write_b32, lane-contiguous
    }
    __syncthreads();

    if (tid < K) {
        double s = 0.0;
        #pragma unroll
        for (int j = 0; j < 8; ++j) s += c2p[tid][j];
        sc2d[tid] = s;
        sc2f[tid] = (float)s;
    }
    __syncthreads();

    // ---- epilogue: wave 0, lane = pixel ----
    if (tid < 64) {
        const int pix = tid;
        float d[K];
        #pragma unroll
        for (int k = 0; k < K; ++k) {
            float s = 0.f;
            #pragma unroll
            for (int w8 = 0; w8 < 8; ++w8)
                s += part[(w8 * K + k) * 64 + pix];
            d[k] = sc2f[k] - 2.0f * s;
        }
        int best = 0; float m1 = d[0];
        #pragma unroll
        for (int k = 1; k < K; ++k) if (d[k] < m1) { m1 = d[k]; best = k; }

        // near-tie candidates within TAU of the f32 min (always includes best)
        unsigned cmask = 0u;
        #pragma unroll
        for (int k = 0; k < K; ++k) if (d[k] - m1 < TAU) cmask |= (1u << k);

        // ---- cooperative exact-f64 resolve of flagged pixels ----
        // ballot is wave-uniform -> the while loop is uniform across wave 0.
        const bool need = (cmask & (cmask - 1)) != 0u;
        unsigned long long ball = __ballot(need);
        while (ball) {
            const int px = (int)__builtin_ctzll(ball);   // lowest flagged lane
            ball &= ball - 1;
            // broadcast that pixel's state to all 64 lanes
            const unsigned pm  = __shfl(cmask, px, 64);
            const int      phw = __shfl(hw,    px, 64);
            const int      pb  = __shfl(b,     px, 64);
            const float* __restrict__ fcol = feat + (size_t)pb * C * HW + phw;

            // lane covers channels 4*lane .. 4*lane+3
            const int c0 = tid << 2;
            double pf[4];
            #pragma unroll
            for (int j = 0; j < 4; ++j)
                pf[j] = (double)fcol[(size_t)(c0 + j) * HW];

            double bd = 1e300; int bi = 0;
            unsigned mm = pm;
            while (mm) {                      // ascending k, strict < tie-break
                const int k = (int)__builtin_ctz(mm);
                mm &= mm - 1;
                const float* __restrict__ ck = cent + (size_t)k * C + c0;
                double s = 0.0;
                #pragma unroll
                for (int j = 0; j < 4; ++j)
                    s = fma(pf[j], (double)ck[j], s);
                // full butterfly: every lane ends with the total sum
                #pragma unroll
                for (int off = 1; off < 64; off <<= 1)
                    s += __shfl_xor(s, off, 64);
                const double dk = sc2d[k] - 2.0 * s;
                if (dk < bd) { bd = dk; bi = k; }
            }
            if (tid == px) best = bi;         // all lanes agree on bi
        }

        // write the 8x8 nearest-upsampled block
        const int w = hw & (WF - 1);
        const int h = hw >> 7;
        int4 v = make_int4(best, best, best, best);
        int* __restrict__ ob = out + (size_t)map * (BB * HL * WL)
                                   + (size_t)b * (HL * WL)
                                   + (size_t)(h * 8) * WL + (size_t)(w * 8);
        #pragma unroll
        for (int r = 0; r < 8; ++r) {
            *(int4*)(ob + (size_t)r * WL)     = v;
            *(int4*)(ob + (size_t)r * WL + 4) = v;
        }
    }
}

extern "C" void kernel_launch(void* const* d_in, const int* in_sizes, int n_in,
                              void* d_out, int out_size, void* d_ws, size_t ws_size,
                              hipStream_t stream) {
    const float* feature_s2t     = (const float*)d_in[0];
    const float* feature_target  = (const float*)d_in[1];
    // d_in[2], d_in[3]: labels — only shapes matter, unused
    const float* centroid_s2t    = (const float*)d_in[4];
    const float* centroid_target = (const float*)d_in[5];
    int* out = (int*)d_out;

    dim3 grid(32768 / 64, 2);   // (512, 2) -> 1024 blocks
    dim3 block(512);
    hipLaunchKernelGGL(centroid_mask_kernel, grid, block, 0, stream,
                       feature_s2t, feature_target,
                       centroid_target, centroid_s2t, out);
}